// Round 8
// baseline (735.271 us; speedup 1.0000x reference)
//
#include <hip/hip_runtime.h>

#define DH 128   // D_IN == D_H == 128
#define TR 32    // rows per tile (per block)

typedef __attribute__((ext_vector_type(8))) short bf16x8;
typedef __attribute__((ext_vector_type(8))) unsigned short u16x8;
typedef __attribute__((ext_vector_type(4))) float f32x4;
typedef __attribute__((ext_vector_type(4))) int   i32x4;

__device__ inline unsigned rnd_bf16(float f){
  unsigned u = __builtin_bit_cast(unsigned, f);
  u += 0x7fffu + ((u >> 16) & 1u);   // RNE
  return u;
}
__device__ inline int pk2(float a, float b){
  unsigned ua = rnd_bf16(a), ub = rnd_bf16(b);
  return (int)((ua >> 16) | (ub & 0xffff0000u));
}
__device__ inline float fsigmoid(float v){
  float e = __builtin_amdgcn_exp2f(v * -1.442695040888963f);
  return __builtin_amdgcn_rcpf(1.0f + e);
}
__device__ inline float ftanhf(float v){
  float e = __builtin_amdgcn_exp2f(v * 2.885390081777927f); // e^{2v}
  return 1.0f - 2.0f * __builtin_amdgcn_rcpf(1.0f + e);
}

// Wf[hs 4][g 4][t 2][ks 8][lane 64] 16B fragments: lane (l15,lg) holds
// ncol = g*128 + hs*32 + t*16 + l15, k = ks*32 + lg*8 .. +8 (k<128: W_x, else W_h).
__global__ void prep_weights(const float* __restrict__ Wxi, const float* __restrict__ Whi, const float* __restrict__ bi,
                             const float* __restrict__ Wxf, const float* __restrict__ Whf, const float* __restrict__ bf_,
                             const float* __restrict__ Wxc, const float* __restrict__ Whc, const float* __restrict__ bc,
                             const float* __restrict__ Wxo, const float* __restrict__ Who, const float* __restrict__ bo,
                             u16x8* __restrict__ Wf, float* __restrict__ bcat){
  int gid  = blockIdx.x * 256 + threadIdx.x;   // 0..16383
  int lane = gid & 63;
  int ks   = (gid >> 6) & 7;
  int t    = (gid >> 9) & 1;
  int g    = (gid >> 10) & 3;
  int hsv  = (gid >> 12) & 3;
  int l15 = lane & 15, lg = lane >> 4;
  int hcol = hsv * 32 + t * 16 + l15;
  int kb   = ks * 32 + lg * 8;
  const float* Wx = (g == 0) ? Wxi : (g == 1) ? Wxf : (g == 2) ? Wxc : Wxo;
  const float* Wh = (g == 0) ? Whi : (g == 1) ? Whf : (g == 2) ? Whc : Who;
  u16x8 o;
  #pragma unroll
  for (int j = 0; j < 8; ++j){
    int k = kb + j;
    float v = (k < 128) ? Wx[k * DH + hcol] : Wh[(k - 128) * DH + hcol];
    o[j] = (unsigned short)(rnd_bf16(v) >> 16);
  }
  Wf[gid] = o;
  if (gid < 512){
    int gg = gid >> 7, hc = gid & 127;
    const float* bp = (gg == 0) ? bi : (gg == 1) ? bf_ : (gg == 2) ? bc : bo;
    bcat[gid] = bp[hc];
  }
}

// One 32-row tile per block. 256 thr = 4 waves; wave w owns h-cols
// [w*32, w*32+32) for ALL 4 gates (lane-local elementwise). All input loads
// and output stores nontemporal (L2 reserved for weights). Epilogue goes
// through LDS so every store is a full-line contiguous dwordx4 burst.
__global__ __launch_bounds__(256, 4)
void lstm_fused(const float* __restrict__ x, const float* __restrict__ hin,
                const float* __restrict__ cin, const bf16x8* __restrict__ Wf,
                const float* __restrict__ bcat, float* __restrict__ out, int Btot){
  __shared__ __attribute__((aligned(16))) unsigned char smem[16384];
  bf16x8* xh  = (bf16x8*)smem;    // staging tile, 32 rows x 32 slots
  float*  tls = (float*)smem;     // epilogue transpose buffer, 32 x 128 f32

  const int tid = threadIdx.x;
  const int l   = tid & 63;
  const int hs  = tid >> 6;        // wave id = col-slice 0..3
  const int l15 = l & 15;
  const int lg  = l >> 4;          // 0..3
  const size_t rowb = (size_t)blockIdx.x * TR;

  // ---- staging loads (nontemporal: read-once)
  const int srow = tid >> 3;       // 0..31
  const int scol = (tid & 7) * 16; // float col base
  const float* px = x   + (rowb + srow) * DH + scol;
  const float* ph = hin + (rowb + srow) * DH + scol;
  f32x4 x0 = __builtin_nontemporal_load((const f32x4*)(px));
  f32x4 x1 = __builtin_nontemporal_load((const f32x4*)(px + 4));
  f32x4 x2 = __builtin_nontemporal_load((const f32x4*)(px + 8));
  f32x4 x3 = __builtin_nontemporal_load((const f32x4*)(px + 12));
  f32x4 h0 = __builtin_nontemporal_load((const f32x4*)(ph));
  f32x4 h1 = __builtin_nontemporal_load((const f32x4*)(ph + 4));
  f32x4 h2 = __builtin_nontemporal_load((const f32x4*)(ph + 8));
  f32x4 h3 = __builtin_nontemporal_load((const f32x4*)(ph + 12));

  // ---- c prefetch (nontemporal)
  float cr[2][2][4];
  #pragma unroll
  for (int m = 0; m < 2; ++m)
    #pragma unroll
    for (int t = 0; t < 2; ++t)
      #pragma unroll
      for (int r = 0; r < 4; ++r)
        cr[m][t][r] = __builtin_nontemporal_load(
            cin + (rowb + m * 16 + lg * 4 + r) * DH + hs * 32 + t * 16 + l15);

  // ---- pack + LDS write (slot swizzle s^(row&7); 2-way max = free)
  {
    const int sw = srow & 7;
    const int s0 = (tid & 7) * 2;        // x-half slots
    i32x4 p;
    p[0] = pk2(x0[0], x0[1]); p[1] = pk2(x0[2], x0[3]);
    p[2] = pk2(x1[0], x1[1]); p[3] = pk2(x1[2], x1[3]);
    xh[srow * 32 + ( s0          ^ sw)] = __builtin_bit_cast(bf16x8, p);
    p[0] = pk2(x2[0], x2[1]); p[1] = pk2(x2[2], x2[3]);
    p[2] = pk2(x3[0], x3[1]); p[3] = pk2(x3[2], x3[3]);
    xh[srow * 32 + ((s0 + 1)     ^ sw)] = __builtin_bit_cast(bf16x8, p);
    p[0] = pk2(h0[0], h0[1]); p[1] = pk2(h0[2], h0[3]);
    p[2] = pk2(h1[0], h1[1]); p[3] = pk2(h1[2], h1[3]);
    xh[srow * 32 + ((16 + s0)    ^ sw)] = __builtin_bit_cast(bf16x8, p);
    p[0] = pk2(h2[0], h2[1]); p[1] = pk2(h2[2], h2[3]);
    p[2] = pk2(h3[0], h3[1]); p[3] = pk2(h3[2], h3[3]);
    xh[srow * 32 + ((16 + s0 + 1)^ sw)] = __builtin_bit_cast(bf16x8, p);
  }
  __syncthreads();

  float bb[4][2];
  #pragma unroll
  for (int g = 0; g < 4; ++g)
    #pragma unroll
    for (int t = 0; t < 2; ++t)
      bb[g][t] = bcat[g * 128 + hs * 32 + t * 16 + l15];

  const bf16x8* wv = Wf + (size_t)hs * 4096 + l;  // [(g*2+t)*8+ks] stride 64

  f32x4 acc[2][4][2];
  #pragma unroll
  for (int m = 0; m < 2; ++m)
    #pragma unroll
    for (int g = 0; g < 4; ++g)
      #pragma unroll
      for (int t = 0; t < 2; ++t)
        acc[m][g][t] = (f32x4){0.f, 0.f, 0.f, 0.f};

  #pragma unroll
  for (int ks = 0; ks < 8; ++ks){
    bf16x8 a[2];
    #pragma unroll
    for (int m = 0; m < 2; ++m){
      const int row = m * 16 + l15;
      a[m] = xh[row * 32 + ((ks * 4 + lg) ^ (row & 7))];
    }
    #pragma unroll
    for (int g = 0; g < 4; ++g){
      #pragma unroll
      for (int t = 0; t < 2; ++t){
        bf16x8 bw = wv[(((g * 2 + t) * 8) + ks) * 64];
        acc[0][g][t] = __builtin_amdgcn_mfma_f32_16x16x32_bf16(a[0], bw, acc[0][g][t], 0, 0, 0);
        acc[1][g][t] = __builtin_amdgcn_mfma_f32_16x16x32_bf16(a[1], bw, acc[1][g][t], 0, 0, 0);
      }
    }
  }
  __syncthreads();   // k-loop LDS reads done everywhere; safe to reuse smem

  // ---- gate math; h -> LDS transpose (swizzle col^((row&7)<<2)); c -> cr
  #pragma unroll
  for (int m = 0; m < 2; ++m){
    #pragma unroll
    for (int r = 0; r < 4; ++r){
      const int rl = m * 16 + lg * 4 + r;       // local row 0..31
      const int swp = (rl & 7) << 2;
      #pragma unroll
      for (int t = 0; t < 2; ++t){
        const int c = hs * 32 + t * 16 + l15;   // col 0..127
        float gi = acc[m][0][t][r] + bb[0][t];
        float gf = acc[m][1][t][r] + bb[1][t];
        float gc = acc[m][2][t][r] + bb[2][t];
        float go = acc[m][3][t][r] + bb[3][t];
        float i_t = fsigmoid(gi);
        float f_t = fsigmoid(gf);
        float g_t = ftanhf(gc);
        float o_t = fsigmoid(go);
        float cn = f_t * cr[m][t][r] + i_t * g_t;
        float hn = o_t * ftanhf(cn);
        tls[rl * DH + (c ^ swp)] = hn;
        cr[m][t][r] = cn;                        // stash c_new
      }
    }
  }
  __syncthreads();

  // ---- store h twice: full-line contiguous NT dwordx4 (4KB/wave/instr)
  const size_t o1 = (size_t)Btot * DH;
  {
    const int sw2 = (srow & 7) << 2;
    float* po = out + (rowb + srow) * DH + scol;
    #pragma unroll
    for (int i = 0; i < 4; ++i){
      f32x4 v = *(const f32x4*)&tls[srow * DH + ((scol + i * 4) ^ sw2)];
      __builtin_nontemporal_store(v, (f32x4*)(po + i * 4));
      __builtin_nontemporal_store(v, (f32x4*)(po + o1 + i * 4));
    }
  }
  __syncthreads();   // h reads done; reuse LDS for c

  #pragma unroll
  for (int m = 0; m < 2; ++m){
    #pragma unroll
    for (int r = 0; r < 4; ++r){
      const int rl = m * 16 + lg * 4 + r;
      const int swp = (rl & 7) << 2;
      #pragma unroll
      for (int t = 0; t < 2; ++t){
        const int c = hs * 32 + t * 16 + l15;
        tls[rl * DH + (c ^ swp)] = cr[m][t][r];
      }
    }
  }
  __syncthreads();

  {
    const int sw2 = (srow & 7) << 2;
    float* po = out + 2 * o1 + (rowb + srow) * DH + scol;
    #pragma unroll
    for (int i = 0; i < 4; ++i){
      f32x4 v = *(const f32x4*)&tls[srow * DH + ((scol + i * 4) ^ sw2)];
      __builtin_nontemporal_store(v, (f32x4*)(po + i * 4));
    }
  }
}

extern "C" void kernel_launch(void* const* d_in, const int* in_sizes, int n_in,
                              void* d_out, int out_size, void* d_ws, size_t ws_size,
                              hipStream_t stream){
  const float* x  = (const float*)d_in[0];
  const float* ht = (const float*)d_in[1];
  const float* ct = (const float*)d_in[2];
  u16x8* Wf   = (u16x8*)d_ws;                        // 16384 * 16B = 256KB
  float* bcat = (float*)((char*)d_ws + 16384 * 16);  // +2KB
  const int Btot = in_sizes[0] / DH;

  prep_weights<<<64, 256, 0, stream>>>(
      (const float*)d_in[3],  (const float*)d_in[4],  (const float*)d_in[5],
      (const float*)d_in[6],  (const float*)d_in[7],  (const float*)d_in[8],
      (const float*)d_in[9],  (const float*)d_in[10], (const float*)d_in[11],
      (const float*)d_in[12], (const float*)d_in[13], (const float*)d_in[14],
      Wf, bcat);

  lstm_fused<<<Btot / TR, 256, 0, stream>>>(x, ht, ct, (const bf16x8*)Wf, bcat,
                                            (float*)d_out, Btot);
}

// Round 9
// 274.252 us; speedup vs baseline: 2.6810x; 2.6810x over previous
//
#include <hip/hip_runtime.h>

#define DH 128   // D_IN == D_H == 128
#define TR 32    // rows per tile (per block)

typedef __attribute__((ext_vector_type(8))) short bf16x8;
typedef __attribute__((ext_vector_type(8))) unsigned short u16x8;
typedef __attribute__((ext_vector_type(4))) float f32x4;
typedef __attribute__((ext_vector_type(4))) int   i32x4;

__device__ inline unsigned rnd_bf16(float f){
  unsigned u = __builtin_bit_cast(unsigned, f);
  u += 0x7fffu + ((u >> 16) & 1u);   // RNE
  return u;
}
__device__ inline int pk2(float a, float b){
  unsigned ua = rnd_bf16(a), ub = rnd_bf16(b);
  return (int)((ua >> 16) | (ub & 0xffff0000u));
}
__device__ inline float fsigmoid(float v){
  float e = __builtin_amdgcn_exp2f(v * -1.442695040888963f);
  return __builtin_amdgcn_rcpf(1.0f + e);
}
__device__ inline float ftanhf(float v){
  float e = __builtin_amdgcn_exp2f(v * 2.885390081777927f); // e^{2v}
  return 1.0f - 2.0f * __builtin_amdgcn_rcpf(1.0f + e);
}

// Wf[hs 4][g 4][t 2][ks 8][lane 64] 16B fragments: lane (l15,lg) holds
// ncol = g*128 + hs*32 + t*16 + l15, k = ks*32 + lg*8 .. +8 (k<128: W_x, else W_h).
__global__ void prep_weights(const float* __restrict__ Wxi, const float* __restrict__ Whi, const float* __restrict__ bi,
                             const float* __restrict__ Wxf, const float* __restrict__ Whf, const float* __restrict__ bf_,
                             const float* __restrict__ Wxc, const float* __restrict__ Whc, const float* __restrict__ bc,
                             const float* __restrict__ Wxo, const float* __restrict__ Who, const float* __restrict__ bo,
                             u16x8* __restrict__ Wf, float* __restrict__ bcat){
  int gid  = blockIdx.x * 256 + threadIdx.x;   // 0..16383
  int lane = gid & 63;
  int ks   = (gid >> 6) & 7;
  int t    = (gid >> 9) & 1;
  int g    = (gid >> 10) & 3;
  int hsv  = (gid >> 12) & 3;
  int l15 = lane & 15, lg = lane >> 4;
  int hcol = hsv * 32 + t * 16 + l15;
  int kb   = ks * 32 + lg * 8;
  const float* Wx = (g == 0) ? Wxi : (g == 1) ? Wxf : (g == 2) ? Wxc : Wxo;
  const float* Wh = (g == 0) ? Whi : (g == 1) ? Whf : (g == 2) ? Whc : Who;
  u16x8 o;
  #pragma unroll
  for (int j = 0; j < 8; ++j){
    int k = kb + j;
    float v = (k < 128) ? Wx[k * DH + hcol] : Wh[(k - 128) * DH + hcol];
    o[j] = (unsigned short)(rnd_bf16(v) >> 16);
  }
  Wf[gid] = o;
  if (gid < 512){
    int gg = gid >> 7, hc = gid & 127;
    const float* bp = (gg == 0) ? bi : (gg == 1) ? bf_ : (gg == 2) ? bc : bo;
    bcat[gid] = bp[hc];
  }
}

// One 32-row tile per block. 256 thr = 4 waves; wave w owns h-cols
// [w*32, w*32+32) for ALL 4 gates (lane-local elementwise). All inputs NT
// loads, outputs NT stores. Epilogue transposes h AND c through LDS so every
// store instruction is 1KiB contiguous (64 lanes x 16B = 8 full lines).
__global__ __launch_bounds__(256, 4)
void lstm_fused(const float* __restrict__ x, const float* __restrict__ hin,
                const float* __restrict__ cin, const bf16x8* __restrict__ Wf,
                const float* __restrict__ bcat, float* __restrict__ out, int Btot){
  __shared__ __attribute__((aligned(16))) unsigned char smem[32768];
  bf16x8* xh  = (bf16x8*)smem;              // staging tile, 32 rows x 32 slots
  float*  hls = (float*)smem;               // epilogue h transpose (reuse)
  float*  cls = (float*)(smem + 16384);     // epilogue c transpose

  const int tid = threadIdx.x;
  const int l   = tid & 63;
  const int hs  = tid >> 6;        // wave id = col-slice 0..3
  const int l15 = l & 15;
  const int lg  = l >> 4;          // 0..3
  const size_t rowb = (size_t)blockIdx.x * TR;

  // ---- staging loads (nontemporal: read-once)
  const int srow = tid >> 3;       // 0..31
  const int scol = (tid & 7) * 16; // float col base
  const float* px = x   + (rowb + srow) * DH + scol;
  const float* ph = hin + (rowb + srow) * DH + scol;
  f32x4 x0 = __builtin_nontemporal_load((const f32x4*)(px));
  f32x4 x1 = __builtin_nontemporal_load((const f32x4*)(px + 4));
  f32x4 x2 = __builtin_nontemporal_load((const f32x4*)(px + 8));
  f32x4 x3 = __builtin_nontemporal_load((const f32x4*)(px + 12));
  f32x4 h0 = __builtin_nontemporal_load((const f32x4*)(ph));
  f32x4 h1 = __builtin_nontemporal_load((const f32x4*)(ph + 4));
  f32x4 h2 = __builtin_nontemporal_load((const f32x4*)(ph + 8));
  f32x4 h3 = __builtin_nontemporal_load((const f32x4*)(ph + 12));

  // ---- c prefetch (nontemporal)
  float cr[2][2][4];
  #pragma unroll
  for (int m = 0; m < 2; ++m)
    #pragma unroll
    for (int t = 0; t < 2; ++t)
      #pragma unroll
      for (int r = 0; r < 4; ++r)
        cr[m][t][r] = __builtin_nontemporal_load(
            cin + (rowb + m * 16 + lg * 4 + r) * DH + hs * 32 + t * 16 + l15);

  // ---- pack + LDS write (slot swizzle s^(row&7); 2-way max = free)
  {
    const int sw = srow & 7;
    const int s0 = (tid & 7) * 2;        // x-half slots
    i32x4 p;
    p[0] = pk2(x0[0], x0[1]); p[1] = pk2(x0[2], x0[3]);
    p[2] = pk2(x1[0], x1[1]); p[3] = pk2(x1[2], x1[3]);
    xh[srow * 32 + ( s0          ^ sw)] = __builtin_bit_cast(bf16x8, p);
    p[0] = pk2(x2[0], x2[1]); p[1] = pk2(x2[2], x2[3]);
    p[2] = pk2(x3[0], x3[1]); p[3] = pk2(x3[2], x3[3]);
    xh[srow * 32 + ((s0 + 1)     ^ sw)] = __builtin_bit_cast(bf16x8, p);
    p[0] = pk2(h0[0], h0[1]); p[1] = pk2(h0[2], h0[3]);
    p[2] = pk2(h1[0], h1[1]); p[3] = pk2(h1[2], h1[3]);
    xh[srow * 32 + ((16 + s0)    ^ sw)] = __builtin_bit_cast(bf16x8, p);
    p[0] = pk2(h2[0], h2[1]); p[1] = pk2(h2[2], h2[3]);
    p[2] = pk2(h3[0], h3[1]); p[3] = pk2(h3[2], h3[3]);
    xh[srow * 32 + ((16 + s0 + 1)^ sw)] = __builtin_bit_cast(bf16x8, p);
  }
  __syncthreads();

  float bb[4][2];
  #pragma unroll
  for (int g = 0; g < 4; ++g)
    #pragma unroll
    for (int t = 0; t < 2; ++t)
      bb[g][t] = bcat[g * 128 + hs * 32 + t * 16 + l15];

  const bf16x8* wv = Wf + (size_t)hs * 4096 + l;  // [(g*2+t)*8+ks] stride 64

  f32x4 acc[2][4][2];
  #pragma unroll
  for (int m = 0; m < 2; ++m)
    #pragma unroll
    for (int g = 0; g < 4; ++g)
      #pragma unroll
      for (int t = 0; t < 2; ++t)
        acc[m][g][t] = (f32x4){0.f, 0.f, 0.f, 0.f};

  #pragma unroll
  for (int ks = 0; ks < 8; ++ks){
    bf16x8 a[2];
    #pragma unroll
    for (int m = 0; m < 2; ++m){
      const int row = m * 16 + l15;
      a[m] = xh[row * 32 + ((ks * 4 + lg) ^ (row & 7))];
    }
    #pragma unroll
    for (int g = 0; g < 4; ++g){
      #pragma unroll
      for (int t = 0; t < 2; ++t){
        bf16x8 bw = wv[(((g * 2 + t) * 8) + ks) * 64];
        acc[0][g][t] = __builtin_amdgcn_mfma_f32_16x16x32_bf16(a[0], bw, acc[0][g][t], 0, 0, 0);
        acc[1][g][t] = __builtin_amdgcn_mfma_f32_16x16x32_bf16(a[1], bw, acc[1][g][t], 0, 0, 0);
      }
    }
  }
  __syncthreads();   // k-loop LDS reads done everywhere; safe to reuse smem

  // ---- gate math; h -> hls, c -> cls (swizzle col^((row&7)<<2))
  #pragma unroll
  for (int m = 0; m < 2; ++m){
    #pragma unroll
    for (int r = 0; r < 4; ++r){
      const int rl = m * 16 + lg * 4 + r;       // local row 0..31
      const int swp = (rl & 7) << 2;
      #pragma unroll
      for (int t = 0; t < 2; ++t){
        const int c = hs * 32 + t * 16 + l15;   // col 0..127
        float gi = acc[m][0][t][r] + bb[0][t];
        float gf = acc[m][1][t][r] + bb[1][t];
        float gc = acc[m][2][t][r] + bb[2][t];
        float go = acc[m][3][t][r] + bb[3][t];
        float i_t = fsigmoid(gi);
        float f_t = fsigmoid(gf);
        float g_t = ftanhf(gc);
        float o_t = fsigmoid(go);
        float cn = f_t * cr[m][t][r] + i_t * g_t;
        float hn = o_t * ftanhf(cn);
        hls[rl * DH + (c ^ swp)] = hn;
        cls[rl * DH + (c ^ swp)] = cn;
      }
    }
  }
  __syncthreads();

  // ---- stores: wave hs owns rows [hs*8, hs*8+8); each instruction:
  // lane l -> row j*2+(l>>5), colf (l&31)*4 => 1KiB contiguous NT burst.
  const size_t o1 = (size_t)Btot * DH;
  const int wcol = (l & 31) * 4;
  #pragma unroll
  for (int j = 0; j < 4; ++j){
    const int row = hs * 8 + j * 2 + (l >> 5);
    const int sw2 = (row & 7) << 2;
    const float* src = &hls[row * DH + (wcol ^ sw2)];
    f32x4 vh = *(const f32x4*)src;
    f32x4 vc = *(const f32x4*)(src + 16384 / 4);   // cls mirrors hls layout
    float* po = out + (rowb + row) * DH + wcol;
    __builtin_nontemporal_store(vh, (f32x4*)(po));
    __builtin_nontemporal_store(vh, (f32x4*)(po + o1));
    __builtin_nontemporal_store(vc, (f32x4*)(po + 2 * o1));
  }
}

extern "C" void kernel_launch(void* const* d_in, const int* in_sizes, int n_in,
                              void* d_out, int out_size, void* d_ws, size_t ws_size,
                              hipStream_t stream){
  const float* x  = (const float*)d_in[0];
  const float* ht = (const float*)d_in[1];
  const float* ct = (const float*)d_in[2];
  u16x8* Wf   = (u16x8*)d_ws;                        // 16384 * 16B = 256KB
  float* bcat = (float*)((char*)d_ws + 16384 * 16);  // +2KB
  const int Btot = in_sizes[0] / DH;

  prep_weights<<<64, 256, 0, stream>>>(
      (const float*)d_in[3],  (const float*)d_in[4],  (const float*)d_in[5],
      (const float*)d_in[6],  (const float*)d_in[7],  (const float*)d_in[8],
      (const float*)d_in[9],  (const float*)d_in[10], (const float*)d_in[11],
      (const float*)d_in[12], (const float*)d_in[13], (const float*)d_in[14],
      Wf, bcat);

  lstm_fused<<<Btot / TR, 256, 0, stream>>>(x, ht, ct, (const bf16x8*)Wf, bcat,
                                            (float*)d_out, Btot);
}